// Round 1
// baseline (79.391 us; speedup 1.0000x reference)
//
#include <hip/hip_runtime.h>

// Depthwise causal conv1d: B=8, T=4096, C=1024, K=4, dilation=1.
// y[b,t,c] = sum_{k=0..3} w[c,k] * x[b, t-3+k, c]   (x zero-padded on the left)
//
// x layout (B,T,C) fp32: channels contiguous -> float4 per thread, 256 threads
// cover C=1024. Each block owns one (b, 32-wide t-tile); sliding window of 3
// float4 in registers so each x row is loaded once (+3 halo rows per tile).

#define T_TILE 32
#define UNROLL 8

__global__ __launch_bounds__(256) void DepthwiseCausalConv1d_57870389346354_kernel(
    const float4* __restrict__ x,   // (B*T*C/4) float4
    const float4* __restrict__ w,   // (C) float4 : channel c's 4 taps
    float4* __restrict__ y,
    int T, int C4)
{
    const int tiles_per_b = T / T_TILE;
    const int tile = blockIdx.x;
    const int b  = tile / tiles_per_b;
    const int t0 = (tile % tiles_per_b) * T_TILE;
    const int c4 = threadIdx.x;              // 0..255 -> channels 4*c4..4*c4+3

    // Taps for the 4 channels this thread owns. weight is (C,4) fp32, so the
    // float4 at index c holds channel c's taps (k=0..3).
    const float4 w0 = w[4 * c4 + 0];   // channel .x
    const float4 w1 = w[4 * c4 + 1];   // channel .y
    const float4 w2 = w[4 * c4 + 2];   // channel .z
    const float4 w3 = w[4 * c4 + 3];   // channel .w

    const float4* xb = x + (size_t)b * T * C4 + c4;
    float4*       yb = y + (size_t)b * T * C4 + c4;

    const float4 zero = make_float4(0.f, 0.f, 0.f, 0.f);
    float4 xm3 = (t0 - 3 >= 0) ? xb[(size_t)(t0 - 3) * C4] : zero;
    float4 xm2 = (t0 - 2 >= 0) ? xb[(size_t)(t0 - 2) * C4] : zero;
    float4 xm1 = (t0 - 1 >= 0) ? xb[(size_t)(t0 - 1) * C4] : zero;

    for (int tt = 0; tt < T_TILE; tt += UNROLL) {
        float4 cur[UNROLL];
#pragma unroll
        for (int u = 0; u < UNROLL; ++u)
            cur[u] = xb[(size_t)(t0 + tt + u) * C4];

#pragma unroll
        for (int u = 0; u < UNROLL; ++u) {
            float4 out;
            out.x = w0.x * xm3.x + w0.y * xm2.x + w0.z * xm1.x + w0.w * cur[u].x;
            out.y = w1.x * xm3.y + w1.y * xm2.y + w1.z * xm1.y + w1.w * cur[u].y;
            out.z = w2.x * xm3.z + w2.y * xm2.z + w2.z * xm1.z + w2.w * cur[u].z;
            out.w = w3.x * xm3.w + w3.y * xm2.w + w3.z * xm1.w + w3.w * cur[u].w;
            yb[(size_t)(t0 + tt + u) * C4] = out;
            xm3 = xm2; xm2 = xm1; xm1 = cur[u];
        }
    }
}

extern "C" void kernel_launch(void* const* d_in, const int* in_sizes, int n_in,
                              void* d_out, int out_size, void* d_ws, size_t ws_size,
                              hipStream_t stream)
{
    (void)in_sizes; (void)n_in; (void)out_size; (void)d_ws; (void)ws_size;
    constexpr int B = 8, T = 4096, C = 1024;

    const float4* x = (const float4*)d_in[0];
    const float4* w = (const float4*)d_in[1];
    float4*       y = (float4*)d_out;

    dim3 block(C / 4);                       // 256 threads = 4 waves
    dim3 grid(B * (T / T_TILE));             // 8 * 128 = 1024 blocks

    DepthwiseCausalConv1d_57870389346354_kernel<<<grid, block, 0, stream>>>(
        x, w, y, T, C / 4);
}

// Round 2
// 48.809 us; speedup vs baseline: 1.6266x; 1.6266x over previous
//
#include <hip/hip_runtime.h>

// Depthwise causal conv1d: B=8, T=4096, C=1024, K=4, dilation=1.
// y[b,t,c] = sum_{k=0..3} w[c,k] * x[b, t-3+k, c]   (x zero-padded on the left)
//
// x layout (B,T,C) fp32: channels contiguous -> float4 per thread, 256 threads
// cover C=1024. Each block owns one (b, 16-wide t-tile); sliding window of 3
// float4 in registers so each x row is read once (+3 halo rows per tile).
//
// Stores are NONTEMPORAL: y is written once and never re-read, and keeping it
// out of L2/L3 leaves the Infinity Cache to hold x (134 MB < 256 MB), so
// repeat dispatches fetch almost nothing from HBM.

#define T_TILE 16
#define UNROLL 8

typedef float f32x4 __attribute__((ext_vector_type(4)));

__global__ __launch_bounds__(256) void DepthwiseCausalConv1d_57870389346354_kernel(
    const float4* __restrict__ x,   // (B*T*C/4) float4
    const float4* __restrict__ w,   // (C) float4 : channel c's 4 taps
    float4* __restrict__ y,
    int T, int C4)
{
    const int tiles_per_b = T / T_TILE;
    const int tile = blockIdx.x;
    const int b  = tile / tiles_per_b;
    const int t0 = (tile % tiles_per_b) * T_TILE;
    const int c4 = threadIdx.x;              // 0..255 -> channels 4*c4..4*c4+3

    // Taps for the 4 channels this thread owns. weight is (C,4) fp32: the
    // float4 at index c holds channel c's taps k=0..3.
    const float4 w0 = w[4 * c4 + 0];
    const float4 w1 = w[4 * c4 + 1];
    const float4 w2 = w[4 * c4 + 2];
    const float4 w3 = w[4 * c4 + 3];

    const float4* xb = x + (size_t)b * T * C4 + c4;
    float4*       yb = y + (size_t)b * T * C4 + c4;

    const float4 zero = make_float4(0.f, 0.f, 0.f, 0.f);
    float4 xm3 = (t0 - 3 >= 0) ? xb[(size_t)(t0 - 3) * C4] : zero;
    float4 xm2 = (t0 - 2 >= 0) ? xb[(size_t)(t0 - 2) * C4] : zero;
    float4 xm1 = (t0 - 1 >= 0) ? xb[(size_t)(t0 - 1) * C4] : zero;

    for (int tt = 0; tt < T_TILE; tt += UNROLL) {
        float4 cur[UNROLL];
#pragma unroll
        for (int u = 0; u < UNROLL; ++u)
            cur[u] = xb[(size_t)(t0 + tt + u) * C4];

#pragma unroll
        for (int u = 0; u < UNROLL; ++u) {
            float4 out;
            out.x = w0.x * xm3.x + w0.y * xm2.x + w0.z * xm1.x + w0.w * cur[u].x;
            out.y = w1.x * xm3.y + w1.y * xm2.y + w1.z * xm1.y + w1.w * cur[u].y;
            out.z = w2.x * xm3.z + w2.y * xm2.z + w2.z * xm1.z + w2.w * cur[u].z;
            out.w = w3.x * xm3.w + w3.y * xm2.w + w3.z * xm1.w + w3.w * cur[u].w;
            // streaming store: bypass cache retention (y is write-once)
            __builtin_nontemporal_store(*(const f32x4*)&out,
                                        (f32x4*)&yb[(size_t)(t0 + tt + u) * C4]);
            xm3 = xm2; xm2 = xm1; xm1 = cur[u];
        }
    }
}

extern "C" void kernel_launch(void* const* d_in, const int* in_sizes, int n_in,
                              void* d_out, int out_size, void* d_ws, size_t ws_size,
                              hipStream_t stream)
{
    (void)in_sizes; (void)n_in; (void)out_size; (void)d_ws; (void)ws_size;
    constexpr int B = 8, T = 4096, C = 1024;

    const float4* x = (const float4*)d_in[0];
    const float4* w = (const float4*)d_in[1];
    float4*       y = (float4*)d_out;

    dim3 block(C / 4);                       // 256 threads = 4 waves
    dim3 grid(B * (T / T_TILE));             // 8 * 256 = 2048 blocks

    DepthwiseCausalConv1d_57870389346354_kernel<<<grid, block, 0, stream>>>(
        x, w, y, T, C / 4);
}

// Round 3
// 48.520 us; speedup vs baseline: 1.6362x; 1.0060x over previous
//
#include <hip/hip_runtime.h>

// Depthwise causal conv1d: B=8, T=4096, C=1024, K=4, dilation=1.
// y[b,t,c] = sum_{k=0..3} w[c,k] * x[b, t-3+k, c]   (x zero-padded on the left)
//
// x layout (B,T,C) fp32: channels contiguous -> float4 per thread, 256 threads
// cover C=1024. Each block owns one (b, 16-wide t-tile).
//
// MLP-first structure: all 19 tile loads (16 rows + 3 halo) are issued
// upfront and fully unrolled (19 float4 = 304 B in flight per wave) so the
// wave never stalls on a half-filled load queue; then 16 nontemporal stores.
// Stores bypass cache retention (y is write-once) so the Infinity Cache
// keeps x lines for the halo reads and across graph replays.

#define T_TILE 16

typedef float f32x4 __attribute__((ext_vector_type(4)));

__global__ __launch_bounds__(256) void DepthwiseCausalConv1d_57870389346354_kernel(
    const float4* __restrict__ x,   // (B*T*C/4) float4
    const float4* __restrict__ w,   // (C) float4 : channel c's 4 taps
    float4* __restrict__ y,
    int T, int C4)
{
    const int tiles_per_b = T / T_TILE;
    const int tile = blockIdx.x;
    const int b  = tile / tiles_per_b;
    const int t0 = (tile % tiles_per_b) * T_TILE;
    const int c4 = threadIdx.x;              // 0..255 -> channels 4*c4..4*c4+3

    // Taps for the 4 channels this thread owns. weight is (C,4) fp32: the
    // float4 at index c holds channel c's taps k=0..3.
    const float4 w0 = w[4 * c4 + 0];
    const float4 w1 = w[4 * c4 + 1];
    const float4 w2 = w[4 * c4 + 2];
    const float4 w3 = w[4 * c4 + 3];

    const float4* xb = x + (size_t)b * T * C4 + c4;
    float4*       yb = y + (size_t)b * T * C4 + c4;

    const float4 zero = make_float4(0.f, 0.f, 0.f, 0.f);

    // ---- issue ALL loads upfront: 3 halo + 16 rows, 19 outstanding ----
    // t0 is a multiple of 16, so t0-3 < 0 only when t0 == 0.
    float4 xm3 = (t0 >= 3) ? xb[(size_t)(t0 - 3) * C4] : zero;
    float4 xm2 = (t0 >= 2) ? xb[(size_t)(t0 - 2) * C4] : zero;
    float4 xm1 = (t0 >= 1) ? xb[(size_t)(t0 - 1) * C4] : zero;

    float4 row[T_TILE];
#pragma unroll
    for (int u = 0; u < T_TILE; ++u)
        row[u] = xb[(size_t)(t0 + u) * C4];

    // ---- compute + streaming stores ----
#pragma unroll
    for (int u = 0; u < T_TILE; ++u) {
        float4 out;
        out.x = w0.x * xm3.x + w0.y * xm2.x + w0.z * xm1.x + w0.w * row[u].x;
        out.y = w1.x * xm3.y + w1.y * xm2.y + w1.z * xm1.y + w1.w * row[u].y;
        out.z = w2.x * xm3.z + w2.y * xm2.z + w2.z * xm1.z + w2.w * row[u].z;
        out.w = w3.x * xm3.w + w3.y * xm2.w + w3.z * xm1.w + w3.w * row[u].w;
        __builtin_nontemporal_store(*(const f32x4*)&out,
                                    (f32x4*)&yb[(size_t)(t0 + u) * C4]);
        xm3 = xm2; xm2 = xm1; xm1 = row[u];
    }
}

extern "C" void kernel_launch(void* const* d_in, const int* in_sizes, int n_in,
                              void* d_out, int out_size, void* d_ws, size_t ws_size,
                              hipStream_t stream)
{
    (void)in_sizes; (void)n_in; (void)out_size; (void)d_ws; (void)ws_size;
    constexpr int B = 8, T = 4096, C = 1024;

    const float4* x = (const float4*)d_in[0];
    const float4* w = (const float4*)d_in[1];
    float4*       y = (float4*)d_out;

    dim3 block(C / 4);                       // 256 threads = 4 waves
    dim3 grid(B * (T / T_TILE));             // 8 * 256 = 2048 blocks

    DepthwiseCausalConv1d_57870389346354_kernel<<<grid, block, 0, stream>>>(
        x, w, y, T, C / 4);
}